// Round 3
// baseline (61.622 us; speedup 1.0000x reference)
//
#include <hip/hip_runtime.h>

#define LL    4096
#define OUTL  8191
#define FPAD  272
#define CB1   2352          // copy1 base (16-dw gap after 2336-dw copy0)
#define RB    4704          // rev-copy base dword
#define BTOP  5887          // rev top x-index (== 7 mod 8)
#define SCR   9856          // reduction scratch base (loop reads top out at 9823)
#define LDSDW 26240         // 102.5 KB static: staged buffers + 64 KB scratch.
                            // 1 block/CU (grid==CU count), so no occupancy cost.
#define UNRL  17            // == max frags/wave (heavy region nch=129, wv=0)

typedef short v8s __attribute__((ext_vector_type(8)));
typedef float v4f __attribute__((ext_vector_type(4)));

__device__ __forceinline__ unsigned bf16b(float f) {
    unsigned u = __builtin_bit_cast(unsigned, f);
    u += 0x7fff + ((u >> 16) & 1);          // RNE
    return u >> 16;
}
__device__ __forceinline__ unsigned pk(float lo, float hi) {
    return bf16b(lo) | (bf16b(hi) << 16);
}
// unit swizzle: colliding lanes (g, g+8, g+16, g+24) -> XOR keys {0,2,4,6}
// => 4 distinct bank-quads; linear under +32k-unit strides (bits 3-4 preserved)
__device__ __forceinline__ int swz(int g) { return g ^ (((g >> 3) & 3) << 1); }

// 2 regions per block: the staged LDS image is region-independent (no T0 in
// any staging address), so staging once and computing two regions halves the
// per-CU staging work vs the 4-blocks/batch layout. Pairs (0,1) and (3,2)
// give every block identical total work (65+129 chunks) -> perfect balance
// at 1 block/CU.
__global__ __launch_bounds__(512, 2)
void selfconv_mfma9(const float* __restrict__ xg, float* __restrict__ outg) {
    __shared__ unsigned lds[LDSDW];
    const int tid  = threadIdx.x;
    const int blk  = blockIdx.x;
    const int b    = blk & 127;
    const int half = blk >> 7;                      // 0: regions {0,1}; 1: {3,2}
    const float* __restrict__ xb = xg + b * LL;

    // ---- fwd staging: thread w covers elements E..E+8, E = 8w-272 ----
#pragma unroll
    for (int rr = 0; rr < 2; ++rr) {
        int w = tid + rr * 512;
        if (w < 584) {
            int E = 8 * w - FPAD;
            float e0,e1,e2,e3,e4,e5,e6,e7,e8;
            if (E >= 0 && E + 8 < LL) {             // fast: vector loads
                float4 fa = *(const float4*)(xb + E);
                float4 fb = *(const float4*)(xb + E + 4);
                e0=fa.x; e1=fa.y; e2=fa.z; e3=fa.w;
                e4=fb.x; e5=fb.y; e6=fb.z; e7=fb.w; e8=xb[E+8];
            } else {                                 // edges: guarded scalars
                float t[9];
#pragma unroll
                for (int k = 0; k < 9; ++k) {
                    int e = E + k;
                    t[k] = (e >= 0 && e < LL) ? xb[e] : 0.f;
                }
                e0=t[0]; e1=t[1]; e2=t[2]; e3=t[3]; e4=t[4];
                e5=t[5]; e6=t[6]; e7=t[7]; e8=t[8];
            }
            // d1 (odd-start pairs) derived from d0 halves via alignbit:
            // bit-identical to re-rounding, ~half the pack VALU work.
            unsigned p0 = pk(e0, e1), p1 = pk(e2, e3);
            unsigned p2 = pk(e4, e5), p3 = pk(e6, e7);
            unsigned b8 = bf16b(e8);
            uint4 d0{p0, p1, p2, p3};
            uint4 d1{(p0 >> 16) | (p1 << 16), (p1 >> 16) | (p2 << 16),
                     (p2 >> 16) | (p3 << 16), (p3 >> 16) | (b8 << 16)};
            *(uint4*)&lds[4 * w]       = d0;
            *(uint4*)&lds[CB1 + 4 * w] = d1;
        }
    }
    // ---- rev staging: unit g holds yr[8g..8g+7] = x[BTOP-8g-7..BTOP-8g] ----
    {
        int g = 224 + tid;                          // in-range units, aligned
        int x0 = BTOP - 7 - 8 * g;                  // 0..4088, float4-aligned
        float4 fa = *(const float4*)(xb + x0);
        float4 fb = *(const float4*)(xb + x0 + 4);
        uint4 o{pk(fb.w, fb.z), pk(fb.y, fb.x), pk(fa.w, fa.z), pk(fa.y, fa.x)};
        *(uint4*)&lds[RB + 4 * swz(g)] = o;
    }
    // ---- zero rev pads: units [0,224) and [736,992) (swizzle-closed) ----
    if (tid < 480) {
        int u = (tid < 224) ? tid : tid + 512;
        *(uint4*)&lds[RB + 4 * u] = uint4{0, 0, 0, 0};
    }
    __syncthreads();

    const int wv = tid >> 6, lane = tid & 63, ln16 = lane & 15, q = lane >> 4;
    float* fs = (float*)lds;
    float* __restrict__ ob = outg + b * OUTL;

    auto ldA = [&](int addr) -> v8s {               // 4 unaligned b32 -> v8s
        union { unsigned x[4]; v8s s; } z;
        z.x[0] = lds[addr];     z.x[1] = lds[addr + 1];
        z.x[2] = lds[addr + 2]; z.x[3] = lds[addr + 3];
        return z.s;
    };

    for (int p = 0; p < 2; ++p) {                   // light region first
        const int rg = half ? (3 - p) : p;
        const int T0 = rg << 11;

        // i-union over the 8 tiles (A +256u, B +512v)
        int mn = 0x7fffffff, mx = -0x7fffffff;
#pragma unroll
        for (int u = 0; u < 2; ++u)
#pragma unroll
            for (int v = 0; v < 4; ++v) {
                int base = T0 + 256 * u + 512 * v;
                int iLo = base - (LL - 1); if (iLo < 0) iLo = 0;
                int iHi = base + 255;      if (iHi > LL - 1) iHi = LL - 1;
                int a = iLo - 256 * u; if (a < mn) mn = a;
                int c2 = iHi - 256 * u; if (c2 > mx) mx = c2;
            }
        const int base_   = mn - 15;
        const int i0start = base_ - ((base_ - 1) & 7);   // == 1 mod 8
        const int nch     = ((mx - i0start) >> 5) + 1;
        const int nw      = (nch - wv + 7) >> 3;         // 8-way split
        const int i0w     = i0start + 32 * wv;

        // A: x[i0 + m + 8q + j], m=ln16 — parity selects fwd copy
        const int s0p = i0w + ln16 + 8 * q + FPAD;
        const int aw  = (s0p >> 1) + ((s0p & 1) ? CB1 : 0);
        // B: yr unit base at v=3; strides preserve the swizzle key
        const int g3 = (4352 - T0 + i0w - 16 * ln16 + 8 * q) >> 3;
        const int bw = RB + 4 * swz(g3);

        v4f a00{0,0,0,0}, a01{0,0,0,0}, a02{0,0,0,0}, a03{0,0,0,0};
        v4f a10{0,0,0,0}, a11{0,0,0,0}, a12{0,0,0,0}, a13{0,0,0,0};

        // ---------------- sliding-window main loop ----------------
        // frag t: A(u) = v8s at aw+128*(t+u); B(v) = v8s at bw+128*(t+2*(3-v))
        // Steady state loads ONE new A tile + ONE new B slot per frag.
        // Max read address aw/bw + 128*23 stays <= 9823 < SCR: pass-2 reads
        // never touch pass-1's reduction scratch.
        v8s Hs[8];                  // H(j) in Hs[j&7]; static idx after unroll
        v8s Ah[3];                  // A(j) in Ah[j%3]
#pragma unroll
        for (int j = 0; j < 7; ++j) Hs[j] = *(const v8s*)&lds[bw + 128 * j];
        Ah[0] = ldA(aw);
        Ah[1] = ldA(aw + 128);

#pragma unroll
        for (int t = 0; t < UNRL; ++t) {
            if (t < nw) {                           // wave-uniform
                if (t + 1 < nw) {                   // prefetch for frag t+1
                    Hs[(t + 7) & 7] = *(const v8s*)&lds[bw + 128 * (t + 7)];
                    Ah[(t + 2) % 3] = ldA(aw + 128 * (t + 2));
                }
                v8s A0 = Ah[t % 3];
                v8s A1 = Ah[(t + 1) % 3];
                v8s B3 = Hs[t & 7],       B2 = Hs[(t + 2) & 7];
                v8s B1 = Hs[(t + 4) & 7], B0 = Hs[(t + 6) & 7];
                __builtin_amdgcn_s_setprio(1);
                a03 = __builtin_amdgcn_mfma_f32_16x16x32_bf16(A0, B3, a03, 0, 0, 0);
                a13 = __builtin_amdgcn_mfma_f32_16x16x32_bf16(A1, B3, a13, 0, 0, 0);
                a02 = __builtin_amdgcn_mfma_f32_16x16x32_bf16(A0, B2, a02, 0, 0, 0);
                a12 = __builtin_amdgcn_mfma_f32_16x16x32_bf16(A1, B2, a12, 0, 0, 0);
                a01 = __builtin_amdgcn_mfma_f32_16x16x32_bf16(A0, B1, a01, 0, 0, 0);
                a11 = __builtin_amdgcn_mfma_f32_16x16x32_bf16(A1, B1, a11, 0, 0, 0);
                a00 = __builtin_amdgcn_mfma_f32_16x16x32_bf16(A0, B0, a00, 0, 0, 0);
                a10 = __builtin_amdgcn_mfma_f32_16x16x32_bf16(A1, B0, a10, 0, 0, 0);
                __builtin_amdgcn_s_setprio(0);
            }
        }

        // ---- single-stage all-to-all reduction (scratch above staging) ----
        // This barrier also orders the PREVIOUS pass's scratch reads against
        // this pass's scratch writes.
        __syncthreads();
        {
            const int lb = SCR + wv * 256 + lane * 4;
            *(v4f*)&fs[0 * 2048 + lb] = a00; *(v4f*)&fs[1 * 2048 + lb] = a10;
            *(v4f*)&fs[2 * 2048 + lb] = a01; *(v4f*)&fs[3 * 2048 + lb] = a11;
            *(v4f*)&fs[4 * 2048 + lb] = a02; *(v4f*)&fs[5 * 2048 + lb] = a12;
            *(v4f*)&fs[6 * 2048 + lb] = a03; *(v4f*)&fs[7 * 2048 + lb] = a13;
        }
        __syncthreads();
        {
            v4f s{0, 0, 0, 0};
            const int tb0 = SCR + wv * 2048 + lane * 4;
#pragma unroll
            for (int w = 0; w < 8; ++w)
                s += *(const v4f*)&fs[tb0 + w * 256];

            const int u = wv & 1, v = wv >> 1;      // tile uv == wv
            const int tilebase = T0 + 256 * u + 512 * v;
            const int tb = tilebase + 16 * ln16 + 4 * q;
            if (tilebase + 255 < OUTL) {
                *(v4f*)&ob[tb] = s;                  // coalesced b128 store
            } else {
#pragma unroll
                for (int r2 = 0; r2 < 4; ++r2)
                    if (tb + r2 < OUTL) ob[tb + r2] = s[r2];
            }
        }
    }
}

extern "C" void kernel_launch(void* const* d_in, const int* in_sizes, int n_in,
                              void* d_out, int out_size, void* d_ws, size_t ws_size,
                              hipStream_t stream) {
    const float* x = (const float*)d_in[0];
    float* out = (float*)d_out;
    selfconv_mfma9<<<dim3(256), dim3(512), 0, stream>>>(x, out);
}

// Round 4
// 60.711 us; speedup vs baseline: 1.0150x; 1.0150x over previous
//
#include <hip/hip_runtime.h>

// REVERT to round-2 best (60.86 us). Round-3 experiment (fold 2 regions/block,
// stage once, 1 block/CU) regressed +0.76 us: at 1 block/CU the serial phases
// (staging round-trip, barriers, reduction) lose their overlap partner; with
// 2 blocks/CU each block's serial phases hide under the other block's MFMA
// stream. Inter-block overlap > staging dedup on this kernel.

#define LL    4096
#define OUTL  8191
#define FPAD  272
#define NPDW  2336          // dwords per fwd copy: elements -272..4399
#define CB1   2352          // copy1 base (16-dw gap)
#define RB    4704          // rev-copy base dword
#define BTOP  5887          // rev top x-index (== 7 mod 8)
#define LDSDW 16384         // 64 KB: loop buffers (<=9824) and 8x8x256-dw
                            // reduction scratch share the allocation.
                            // 2 blocks/CU retained (128 KB <= 160 KB).
#define UNRL  17            // >= max frags/wave

typedef short v8s __attribute__((ext_vector_type(8)));
typedef float v4f __attribute__((ext_vector_type(4)));

__device__ __forceinline__ unsigned bf16b(float f) {
    unsigned u = __builtin_bit_cast(unsigned, f);
    u += 0x7fff + ((u >> 16) & 1);          // RNE
    return u >> 16;
}
__device__ __forceinline__ unsigned pk(float lo, float hi) {
    return bf16b(lo) | (bf16b(hi) << 16);
}
// unit swizzle: colliding lanes (g, g+8, g+16, g+24) -> XOR keys {0,2,4,6}
// => 4 distinct bank-quads; linear under +32k-unit strides (bits 3-4 preserved)
__device__ __forceinline__ int swz(int g) { return g ^ (((g >> 3) & 3) << 1); }

__global__ __launch_bounds__(512, 4)
void selfconv_mfma10(const float* __restrict__ xg, float* __restrict__ outg) {
    __shared__ unsigned lds[LDSDW];
    const int tid = threadIdx.x;
    const int blk = blockIdx.x;
    const int b   = blk & 127;
    const int id  = blk >> 7;                       // light regions first
    const int rg  = (id == 0) ? 0 : (id == 1) ? 3 : (id == 2) ? 1 : 2;
    const int T0  = rg << 11;
    const float* __restrict__ xb = xg + b * LL;

    // ---- fwd staging: thread w covers elements E..E+8, E = 8w-272 ----
#pragma unroll
    for (int rr = 0; rr < 2; ++rr) {
        int w = tid + rr * 512;
        if (w < 584) {
            int E = 8 * w - FPAD;
            float e0,e1,e2,e3,e4,e5,e6,e7,e8;
            if (E >= 0 && E + 8 < LL) {             // fast: vector loads
                float4 fa = *(const float4*)(xb + E);
                float4 fb = *(const float4*)(xb + E + 4);
                e0=fa.x; e1=fa.y; e2=fa.z; e3=fa.w;
                e4=fb.x; e5=fb.y; e6=fb.z; e7=fb.w; e8=xb[E+8];
            } else {                                 // edges: guarded scalars
                float t[9];
#pragma unroll
                for (int k = 0; k < 9; ++k) {
                    int e = E + k;
                    t[k] = (e >= 0 && e < LL) ? xb[e] : 0.f;
                }
                e0=t[0]; e1=t[1]; e2=t[2]; e3=t[3]; e4=t[4];
                e5=t[5]; e6=t[6]; e7=t[7]; e8=t[8];
            }
            // d1 (odd-start pairs) derived from d0 halves via alignbit:
            // bit-identical to re-rounding, ~half the pack VALU work.
            unsigned p0 = pk(e0, e1), p1 = pk(e2, e3);
            unsigned p2 = pk(e4, e5), p3 = pk(e6, e7);
            unsigned b8 = bf16b(e8);
            uint4 d0{p0, p1, p2, p3};
            uint4 d1{(p0 >> 16) | (p1 << 16), (p1 >> 16) | (p2 << 16),
                     (p2 >> 16) | (p3 << 16), (p3 >> 16) | (b8 << 16)};
            *(uint4*)&lds[4 * w]       = d0;
            *(uint4*)&lds[CB1 + 4 * w] = d1;
        }
    }
    // ---- rev staging: unit g holds yr[8g..8g+7] = x[BTOP-8g-7..BTOP-8g] ----
    {
        int g = 224 + tid;                          // in-range units, aligned
        int x0 = BTOP - 7 - 8 * g;                  // 0..4088, float4-aligned
        float4 fa = *(const float4*)(xb + x0);
        float4 fb = *(const float4*)(xb + x0 + 4);
        uint4 o{pk(fb.w, fb.z), pk(fb.y, fb.x), pk(fa.w, fa.z), pk(fa.y, fa.x)};
        *(uint4*)&lds[RB + 4 * swz(g)] = o;
    }
    // ---- zero rev pads: units [0,224) and [736,992) (swizzle-closed) ----
    if (tid < 480) {
        int u = (tid < 224) ? tid : tid + 512;
        *(uint4*)&lds[RB + 4 * u] = uint4{0, 0, 0, 0};
    }
    __syncthreads();

    const int wv = tid >> 6, lane = tid & 63, ln16 = lane & 15, q = lane >> 4;

    // i-union over the 8 tiles (A +256u, B +512v)
    int mn = 0x7fffffff, mx = -0x7fffffff;
#pragma unroll
    for (int u = 0; u < 2; ++u)
#pragma unroll
        for (int v = 0; v < 4; ++v) {
            int base = T0 + 256 * u + 512 * v;
            int iLo = base - (LL - 1); if (iLo < 0) iLo = 0;
            int iHi = base + 255;      if (iHi > LL - 1) iHi = LL - 1;
            int a = iLo - 256 * u; if (a < mn) mn = a;
            int c2 = iHi - 256 * u; if (c2 > mx) mx = c2;
        }
    const int base_   = mn - 15;
    const int i0start = base_ - ((base_ - 1) & 7);   // == 1 mod 8
    const int nch     = ((mx - i0start) >> 5) + 1;
    const int nw      = (nch - wv + 7) >> 3;         // 8-way interleaved split
    const int i0w     = i0start + 32 * wv;

    // A: x[i0 + m + 8q + j], m=ln16 — parity selects fwd copy
    const int s0p = i0w + ln16 + 8 * q + FPAD;
    const int aw  = (s0p >> 1) + ((s0p & 1) ? CB1 : 0);
    // B: yr unit base at v=3; subsequent strides all preserve the swizzle key
    const int g3 = (4352 - T0 + i0w - 16 * ln16 + 8 * q) >> 3;   // 4352=BTOP-1535
    const int bw = RB + 4 * swz(g3);

    v4f a00{0,0,0,0}, a01{0,0,0,0}, a02{0,0,0,0}, a03{0,0,0,0};
    v4f a10{0,0,0,0}, a11{0,0,0,0}, a12{0,0,0,0}, a13{0,0,0,0};

    auto ldA = [&](int addr) -> v8s {               // 4 unaligned b32 -> v8s
        union { unsigned x[4]; v8s s; } z;
        z.x[0] = lds[addr];     z.x[1] = lds[addr + 1];
        z.x[2] = lds[addr + 2]; z.x[3] = lds[addr + 3];
        return z.s;
    };

    // ---------------- sliding-window main loop ----------------
    // frag t (t = 0..nw-1):
    //   A(u)  = v8s at aw + 128*(t+u)            -> A(t+1) reused as next A0
    //   B(v)  = v8s at bw + 128*(t + 2*(3-v))    -> slots H(j), j = t..t+6
    // Steady state loads ONE new A tile + ONE new B slot per frag.
    v8s Hs[8];                      // H(j) in Hs[j&7]; static idx after unroll
    v8s Ah[3];                      // A(j) in Ah[j%3]
#pragma unroll
    for (int j = 0; j < 7; ++j) Hs[j] = *(const v8s*)&lds[bw + 128 * j];
    Ah[0] = ldA(aw);
    Ah[1] = ldA(aw + 128);

#pragma unroll
    for (int t = 0; t < UNRL; ++t) {
        if (t < nw) {                               // wave-uniform
            if (t + 1 < nw) {                       // prefetch for frag t+1
                Hs[(t + 7) & 7] = *(const v8s*)&lds[bw + 128 * (t + 7)];
                Ah[(t + 2) % 3] = ldA(aw + 128 * (t + 2));
            }
            v8s A0 = Ah[t % 3];
            v8s A1 = Ah[(t + 1) % 3];
            v8s B3 = Hs[t & 7],       B2 = Hs[(t + 2) & 7];
            v8s B1 = Hs[(t + 4) & 7], B0 = Hs[(t + 6) & 7];
            __builtin_amdgcn_s_setprio(1);
            a03 = __builtin_amdgcn_mfma_f32_16x16x32_bf16(A0, B3, a03, 0, 0, 0);
            a13 = __builtin_amdgcn_mfma_f32_16x16x32_bf16(A1, B3, a13, 0, 0, 0);
            a02 = __builtin_amdgcn_mfma_f32_16x16x32_bf16(A0, B2, a02, 0, 0, 0);
            a12 = __builtin_amdgcn_mfma_f32_16x16x32_bf16(A1, B2, a12, 0, 0, 0);
            a01 = __builtin_amdgcn_mfma_f32_16x16x32_bf16(A0, B1, a01, 0, 0, 0);
            a11 = __builtin_amdgcn_mfma_f32_16x16x32_bf16(A1, B1, a11, 0, 0, 0);
            a00 = __builtin_amdgcn_mfma_f32_16x16x32_bf16(A0, B0, a00, 0, 0, 0);
            a10 = __builtin_amdgcn_mfma_f32_16x16x32_bf16(A1, B0, a10, 0, 0, 0);
            __builtin_amdgcn_s_setprio(0);
        }
    }

    // ---- single-stage all-to-all reduction, 2 barriers total ----
    // Every wave writes its 8 partial tiles to scratch[tile][wave][lane*4]
    // (contiguous 1 KB per wave-instr: conflict-free). After one barrier,
    // wave wv sums tile wv over all 8 waves and stores it directly.
    float* fs = (float*)lds;
    __syncthreads();
    {
        const int lb = wv * 256 + lane * 4;
        *(v4f*)&fs[0 * 2048 + lb] = a00; *(v4f*)&fs[1 * 2048 + lb] = a10;
        *(v4f*)&fs[2 * 2048 + lb] = a01; *(v4f*)&fs[3 * 2048 + lb] = a11;
        *(v4f*)&fs[4 * 2048 + lb] = a02; *(v4f*)&fs[5 * 2048 + lb] = a12;
        *(v4f*)&fs[6 * 2048 + lb] = a03; *(v4f*)&fs[7 * 2048 + lb] = a13;
    }
    __syncthreads();
    {
        v4f s{0, 0, 0, 0};
        const int tb0 = wv * 2048 + lane * 4;
#pragma unroll
        for (int w = 0; w < 8; ++w)
            s += *(const v4f*)&fs[tb0 + w * 256];

        const int u = wv & 1, v = wv >> 1;          // tile uv == wv
        const int tilebase = T0 + 256 * u + 512 * v;
        const int tb = tilebase + 16 * ln16 + 4 * q;
        float* __restrict__ ob = outg + b * OUTL;
        if (tilebase + 255 < OUTL) {
            *(v4f*)&ob[tb] = s;                      // coalesced b128 store
        } else {
#pragma unroll
            for (int r2 = 0; r2 < 4; ++r2)
                if (tb + r2 < OUTL) ob[tb + r2] = s[r2];
        }
    }
}

extern "C" void kernel_launch(void* const* d_in, const int* in_sizes, int n_in,
                              void* d_out, int out_size, void* d_ws, size_t ws_size,
                              hipStream_t stream) {
    const float* x = (const float*)d_in[0];
    float* out = (float*)d_out;
    selfconv_mfma10<<<dim3(512), dim3(512), 0, stream>>>(x, out);
}